// Round 1
// baseline (704.374 us; speedup 1.0000x reference)
//
#include <hip/hip_runtime.h>

#define N_NODES 8192
#define BATCH   32
#define MAX_STEPS 50
#define LEAK    0.01f
#define CAP     64          // max in-degree capacity (avg 16, Poisson tail -> 64 is safe)

// ---------------- workspace layout (float units) ----------------
// Xb      : [0,        262144)   X_bias[t][b] = X_full[b][t] + bias[t]
// X0      : [262144,   524288)   state ping
// X1      : [524288,   786432)   state pong
// deg     : [786432,   794624)   (int) in-degree per target
// csr_src : [794624,  1318912)   (int) source index per edge slot
// csr_w   : [1318912, 1843200)   weight per edge slot
// total: 1843200 floats = 7.03 MB

// Build X_bias with an LDS transpose: read X_full[b][t] coalesced,
// write Xb[t][b] coalesced.
__global__ void bias_kernel(const float* __restrict__ Xf,
                            const float* __restrict__ bias,
                            float* __restrict__ Xb) {
    __shared__ float tile[64 * 33];
    int t0 = blockIdx.x * 64;
    int j = threadIdx.x;                       // 256 threads
    #pragma unroll
    for (int i = 0; i < 8; ++i) {
        int k = j + 256 * i;                   // 0..2047
        int b = k >> 6;                        // 0..31 (row of X_full)
        int c = k & 63;                        // 0..63 (col offset)
        tile[c * 33 + b] = Xf[b * N_NODES + t0 + c];   // coalesced 256B reads
    }
    __syncthreads();
    #pragma unroll
    for (int i = 0; i < 8; ++i) {
        int m = j + 256 * i;                   // element (tl, b)
        int tl = m >> 5;                       // 0..63
        int b  = m & 31;
        Xb[(t0 + tl) * BATCH + b] = tile[tl * 33 + b] + bias[t0 + tl]; // coalesced
    }
}

// One block per target row: scan the dense weight row, compact nonzeros.
// (weights is exactly W: built by scattering nonzero values into zeros.)
__global__ void csr_kernel(const float* __restrict__ W,
                           int* __restrict__ deg,
                           int* __restrict__ csr_src,
                           float* __restrict__ csr_w) {
    __shared__ int cnt;
    int t = blockIdx.x;
    if (threadIdx.x == 0) cnt = 0;
    __syncthreads();
    const float4* row = (const float4*)(W + (size_t)t * N_NODES);
    #pragma unroll
    for (int i = threadIdx.x; i < N_NODES / 4; i += 256) {
        float4 v = row[i];
        if (v.x != 0.f) { int p = atomicAdd(&cnt, 1); if (p < CAP) { csr_src[t*CAP+p] = 4*i+0; csr_w[t*CAP+p] = v.x; } }
        if (v.y != 0.f) { int p = atomicAdd(&cnt, 1); if (p < CAP) { csr_src[t*CAP+p] = 4*i+1; csr_w[t*CAP+p] = v.y; } }
        if (v.z != 0.f) { int p = atomicAdd(&cnt, 1); if (p < CAP) { csr_src[t*CAP+p] = 4*i+2; csr_w[t*CAP+p] = v.z; } }
        if (v.w != 0.f) { int p = atomicAdd(&cnt, 1); if (p < CAP) { csr_src[t*CAP+p] = 4*i+3; csr_w[t*CAP+p] = v.w; } }
    }
    __syncthreads();
    if (threadIdx.x == 0) deg[t] = cnt > CAP ? CAP : cnt;
}

// One recurrence step: thread (t,b) with b = tid&31.
// X, Xn layout: [t][b] (32 floats per node, contiguous).
__global__ void step_kernel(const float* __restrict__ X,
                            float* __restrict__ Xn,
                            const float* __restrict__ Xb,
                            const int* __restrict__ deg,
                            const int* __restrict__ csr_src,
                            const float* __restrict__ csr_w) {
    int id = blockIdx.x * 256 + threadIdx.x;   // 0..262143
    int t = id >> 5;
    int b = id & 31;
    int d = deg[t];                            // broadcast within 32-lane group
    float s = Xb[id];
    const int*   sp = csr_src + t * CAP;
    const float* wp = csr_w   + t * CAP;
    for (int e = 0; e < d; ++e) {
        s += wp[e] * X[sp[e] * BATCH + b];     // 128B coalesced gather per group
    }
    // mml activation
    float r;
    if (s < 0.f)        r = LEAK * s;
    else if (s < 0.5f)  r = s;
    else                r = 1.f - 0.25f / s;
    Xn[id] = r;
}

// Final transpose: out[b][t] = X[t][b], via LDS tile.
__global__ void out_kernel(const float* __restrict__ X,
                           float* __restrict__ out) {
    __shared__ float tile[64 * 33];
    int t0 = blockIdx.x * 64;
    int j = threadIdx.x;
    #pragma unroll
    for (int i = 0; i < 8; ++i) {
        int m = j + 256 * i;
        int tl = m >> 5;
        int b  = m & 31;
        tile[tl * 33 + b] = X[(t0 + tl) * BATCH + b];  // coalesced read
    }
    __syncthreads();
    #pragma unroll
    for (int i = 0; i < 8; ++i) {
        int k = j + 256 * i;
        int b = k >> 6;
        int c = k & 63;
        out[b * N_NODES + t0 + c] = tile[c * 33 + b];  // coalesced 256B writes
    }
}

extern "C" void kernel_launch(void* const* d_in, const int* in_sizes, int n_in,
                              void* d_out, int out_size, void* d_ws, size_t ws_size,
                              hipStream_t stream) {
    const float* X_full  = (const float*)d_in[0];   // (32, 8192)
    const float* weights = (const float*)d_in[1];   // (8192, 8192), == masked W
    const float* bias    = (const float*)d_in[2];   // (8192,)
    // d_in[3] = edge_mask: redundant (weights already zero off-edge), unused.

    float* ws = (float*)d_ws;
    float* Xb      = ws;
    float* X0      = ws + 262144;
    float* X1      = ws + 524288;
    int*   deg     = (int*)(ws + 786432);
    int*   csr_src = (int*)(ws + 794624);
    float* csr_w   = ws + 1318912;

    float* out = (float*)d_out;

    // X_bias build (independent of CSR build)
    bias_kernel<<<N_NODES / 64, 256, 0, stream>>>(X_full, bias, Xb);
    // CSR build from dense weights
    csr_kernel<<<N_NODES, 256, 0, stream>>>(weights, deg, csr_src, csr_w);
    // X0 = zeros
    hipMemsetAsync(X0, 0, 262144 * sizeof(float), stream);

    // 50 recurrence steps, ping-pong
    for (int s = 0; s < MAX_STEPS; ++s) {
        const float* xin = (s & 1) ? X1 : X0;
        float*       xout = (s & 1) ? X0 : X1;
        step_kernel<<<(N_NODES * BATCH) / 256, 256, 0, stream>>>(
            xin, xout, Xb, deg, csr_src, csr_w);
    }
    // MAX_STEPS even -> final state in X0
    out_kernel<<<N_NODES / 64, 256, 0, stream>>>(X0, out);
}

// Round 2
// 323.881 us; speedup vs baseline: 2.1748x; 2.1748x over previous
//
#include <hip/hip_runtime.h>

#define N_NODES 8192
#define BATCH   32
#define MAX_STEPS 50
#define LEAK    0.01f
#define CAP     64          // padded max in-degree (avg 16, Poisson tail safe)

// ---------------- workspace layout (float units) ----------------
// Xb      : [0,        262144)   X_bias[t][b] = X_full[b][t] + bias[t]
// X0      : [262144,   524288)   state ping
// X1      : [524288,   786432)   state pong
// deg8    : [786432,   794624)   (int) number of 8-edge groups per target
// csr_src : [794624,  1318912)   (int) source index per edge slot (8192*64)
// csr_w   : [1318912, 1843200)   weight per edge slot
// total: 7.03 MB

__global__ void bias_kernel(const float* __restrict__ Xf,
                            const float* __restrict__ bias,
                            float* __restrict__ Xb) {
    __shared__ float tile[64 * 33];
    int t0 = blockIdx.x * 64;
    int j = threadIdx.x;                       // 256 threads
    #pragma unroll
    for (int i = 0; i < 8; ++i) {
        int k = j + 256 * i;                   // 0..2047
        int b = k >> 6;                        // 0..31
        int c = k & 63;
        tile[c * 33 + b] = Xf[b * N_NODES + t0 + c];   // coalesced read
    }
    __syncthreads();
    #pragma unroll
    for (int i = 0; i < 8; ++i) {
        int m = j + 256 * i;
        int tl = m >> 5;
        int b  = m & 31;
        Xb[(t0 + tl) * BATCH + b] = tile[tl * 33 + b] + bias[t0 + tl]; // coalesced
    }
}

// One block per target row: scan dense weight row, compact nonzeros,
// pad to a multiple of 8 edges with (src=0, w=0) dummies.
__global__ void csr_kernel(const float* __restrict__ W,
                           int* __restrict__ deg8,
                           int* __restrict__ csr_src,
                           float* __restrict__ csr_w) {
    __shared__ int cnt;
    int t = blockIdx.x;
    if (threadIdx.x == 0) cnt = 0;
    __syncthreads();
    const float4* row = (const float4*)(W + (size_t)t * N_NODES);
    for (int i = threadIdx.x; i < N_NODES / 4; i += 256) {
        float4 v = row[i];
        if (v.x != 0.f) { int p = atomicAdd(&cnt, 1); if (p < CAP) { csr_src[t*CAP+p] = 4*i+0; csr_w[t*CAP+p] = v.x; } }
        if (v.y != 0.f) { int p = atomicAdd(&cnt, 1); if (p < CAP) { csr_src[t*CAP+p] = 4*i+1; csr_w[t*CAP+p] = v.y; } }
        if (v.z != 0.f) { int p = atomicAdd(&cnt, 1); if (p < CAP) { csr_src[t*CAP+p] = 4*i+2; csr_w[t*CAP+p] = v.z; } }
        if (v.w != 0.f) { int p = atomicAdd(&cnt, 1); if (p < CAP) { csr_src[t*CAP+p] = 4*i+3; csr_w[t*CAP+p] = v.w; } }
    }
    __syncthreads();
    if (threadIdx.x == 0) {
        int c = cnt > CAP ? CAP : cnt;
        int c8 = (c + 7) & ~7;                 // pad to multiple of 8
        for (int p = c; p < c8; ++p) { csr_src[t*CAP+p] = 0; csr_w[t*CAP+p] = 0.f; }
        deg8[t] = c8 >> 3;
    }
}

// Step 1 shortcut: X0 = 0 so first iterate is just mml(X_bias).
__global__ void act_kernel(const float* __restrict__ Xb, float* __restrict__ Xn) {
    int id = blockIdx.x * 256 + threadIdx.x;
    float s = Xb[id];
    Xn[id] = (s < 0.f) ? LEAK * s : (s < 0.5f ? s : 1.f - 0.25f / s);
}

// One recurrence step: thread (t,b), b = tid&31. 8-edge groups give 8
// independent gathers per loop iteration (dependent-chain depth ~d/8).
__global__ void step_kernel(const float* __restrict__ X,
                            float* __restrict__ Xn,
                            const float* __restrict__ Xb,
                            const int* __restrict__ deg8,
                            const int* __restrict__ csr_src,
                            const float* __restrict__ csr_w) {
    int id = blockIdx.x * 256 + threadIdx.x;   // 0..262143
    int t = id >> 5;
    int b = id & 31;
    int d8 = deg8[t];                          // uniform within 32-lane group
    const int4*   sp4 = (const int4*)(csr_src + t * CAP);
    const float4* wp4 = (const float4*)(csr_w  + t * CAP);
    float s = Xb[id];
    for (int g = 0; g < d8; ++g) {
        int4   i0 = sp4[2*g], i1 = sp4[2*g+1];
        float4 w0 = wp4[2*g], w1 = wp4[2*g+1];
        float x0 = X[i0.x*BATCH+b], x1 = X[i0.y*BATCH+b];
        float x2 = X[i0.z*BATCH+b], x3 = X[i0.w*BATCH+b];
        float x4 = X[i1.x*BATCH+b], x5 = X[i1.y*BATCH+b];
        float x6 = X[i1.z*BATCH+b], x7 = X[i1.w*BATCH+b];
        s += w0.x*x0 + w0.y*x1 + w0.z*x2 + w0.w*x3
           + w1.x*x4 + w1.y*x5 + w1.z*x6 + w1.w*x7;
    }
    Xn[id] = (s < 0.f) ? LEAK * s : (s < 0.5f ? s : 1.f - 0.25f / s);
}

// Final transpose: out[b][t] = X[t][b].
__global__ void out_kernel(const float* __restrict__ X,
                           float* __restrict__ out) {
    __shared__ float tile[64 * 33];
    int t0 = blockIdx.x * 64;
    int j = threadIdx.x;
    #pragma unroll
    for (int i = 0; i < 8; ++i) {
        int m = j + 256 * i;
        int tl = m >> 5;
        int b  = m & 31;
        tile[tl * 33 + b] = X[(t0 + tl) * BATCH + b];  // coalesced read
    }
    __syncthreads();
    #pragma unroll
    for (int i = 0; i < 8; ++i) {
        int k = j + 256 * i;
        int b = k >> 6;
        int c = k & 63;
        out[b * N_NODES + t0 + c] = tile[c * 33 + b];  // coalesced write
    }
}

extern "C" void kernel_launch(void* const* d_in, const int* in_sizes, int n_in,
                              void* d_out, int out_size, void* d_ws, size_t ws_size,
                              hipStream_t stream) {
    const float* X_full  = (const float*)d_in[0];   // (32, 8192)
    const float* weights = (const float*)d_in[1];   // (8192, 8192), == masked W
    const float* bias    = (const float*)d_in[2];   // (8192,)
    // d_in[3] = edge_mask: redundant (weights already zero off-edge), unused.

    float* ws = (float*)d_ws;
    float* Xb      = ws;
    float* X0      = ws + 262144;
    float* X1      = ws + 524288;
    int*   deg8    = (int*)(ws + 786432);
    int*   csr_src = (int*)(ws + 794624);
    float* csr_w   = ws + 1318912;

    float* out = (float*)d_out;

    bias_kernel<<<N_NODES / 64, 256, 0, stream>>>(X_full, bias, Xb);
    csr_kernel<<<N_NODES, 256, 0, stream>>>(weights, deg8, csr_src, csr_w);

    // step 0 (X starts at zero): X1 = mml(Xb)
    act_kernel<<<(N_NODES * BATCH) / 256, 256, 0, stream>>>(Xb, X1);

    // steps 1..49, ping-pong; final (s=49, odd) lands in X0
    for (int s = 1; s < MAX_STEPS; ++s) {
        const float* xin  = (s & 1) ? X1 : X0;
        float*       xout = (s & 1) ? X0 : X1;
        step_kernel<<<(N_NODES * BATCH) / 256, 256, 0, stream>>>(
            xin, xout, Xb, deg8, csr_src, csr_w);
    }
    out_kernel<<<N_NODES / 64, 256, 0, stream>>>(X0, out);
}